// Round 16
// baseline (316.978 us; speedup 1.0000x reference)
//
#include <hip/hip_runtime.h>
#include <hip/hip_bf16.h>

#define D_ 128
#define NQ_ 256
#define NK_ 2048
#define P_TOT (NQ_ * NK_)   // 524288

typedef float f32x4 __attribute__((ext_vector_type(4)));
typedef short bf16x4 __attribute__((ext_vector_type(4)));

#if __has_builtin(__builtin_amdgcn_mfma_f32_16x16x16_bf16)
#define MFMA16(a, b, c) __builtin_amdgcn_mfma_f32_16x16x16_bf16((a), (b), (c), 0, 0, 0)
#else
#define MFMA16(a, b, c) __builtin_amdgcn_mfma_f32_16x16x16bf16_1k((a), (b), (c), 0, 0, 0)
#endif

__device__ __forceinline__ unsigned short f2bf(float x) {
    union { float f; unsigned u; } v; v.f = x;
    unsigned r = v.u + 0x7FFFu + ((v.u >> 16) & 1u);   // RNE
    return (unsigned short)(r >> 16);
}

// async global->LDS, 16B per lane (wave-uniform LDS base, per-lane global addr)
__device__ __forceinline__ void gload16(const float* g, float* l) {
    __builtin_amdgcn_global_load_lds((const __attribute__((address_space(1))) void*)g,
                                     (__attribute__((address_space(3))) void*)l, 16, 0, 0);
}

#define WAITVM_(n) asm volatile("s_waitcnt vmcnt(" #n ")" ::: "memory")
#define WAITVM(n) WAITVM_(n)

// ---------------- prep: minw init + qb + kh + p1 ----------------
__global__ __launch_bounds__(256) void k_prep(
    const float* __restrict__ w1, const float* __restrict__ x,
    const float* __restrict__ b1, const float* __restrict__ src,
    const float* __restrict__ w3, const float* __restrict__ b3,
    float* __restrict__ qb, float* __restrict__ kh, float* __restrict__ p1,
    unsigned* __restrict__ minw) {
    int b = blockIdx.x, t = threadIdx.x;
    if (b == 0 && t == 0) *minw = 0xFFFFFFFFu;
    if (b < 128) {
        int o = b, n = t;
        const float* wr = w1 + o * 384;
        float acc = b1[o];
#pragma unroll 4
        for (int c = 0; c < 128; ++c) acc = fmaf(wr[c], x[c * 256 + n], acc);
        qb[o * 256 + n] = acc;
    } else if (b < 1152) {
        int idx = (b - 128) * 256 + t;
        int o = idx >> 11, m = idx & 2047;
        const float* wr = w1 + o * 384 + 128;
        float acc = 0.f;
#pragma unroll 4
        for (int c = 0; c < 128; ++c) acc = fmaf(wr[c], src[c * 2048 + m], acc);
        kh[o * 2048 + m] = acc;
    } else {
        int o = b - 1152, n = t;
        const float* wr = w3 + o * 256;
        float acc = b3[o];
#pragma unroll 4
        for (int c = 0; c < 128; ++c) acc = fmaf(wr[c], x[c * 256 + n], acc);
        p1[o * 256 + n] = acc;
    }
}

// ---------------- scores (raw) + global min ----------------
// CHANNEL-SPREAD probe: 512-thr blocks, 512-m x 4-n window, grid 256.
// Slot = [16ch][512m] f32 (32 KB); each wave stages 2 rows, each row ONE
// 2KB-contiguous run (2 gloads) -- doubles the simultaneous p-window (1->2KB)
// to spread each tile's 16 x 2MB-strided streams over 2x the HBM channels.
// 8 waves x 64 m/wave (acc[4][8], static), K=16 MFMA (R12-verified layout),
// ring-3, vmcnt(8). XOR swizzle key=(row&7) on 16B groups, both sides.
// Failure signature (allocator clamp): VGPR<=128 + WRITE_SIZE>50MB -> void.
__global__ __launch_bounds__(512, 2) void k_scores(
    const float* __restrict__ dist, const float* __restrict__ w1,
    const float* __restrict__ qb, const float* __restrict__ kh,
    const float* __restrict__ w2, const float* __restrict__ b2,
    float* __restrict__ scores, unsigned* __restrict__ minw) {
    __shared__ __align__(16) float lds[33408];   // 133632 B
    // [0..8191]       : A-fragments, 4096 x bf16x4 (32 KB), persistent
    // [8192..32767]   : 3 x [16ch][512m] f32 slot ring (96 KB)
    // [32768..33279]  : qbT [4][128]
    // [33280..33407]  : w2l [128]
    float* ring = lds + 8192;
    float* qbT  = lds + 32768;
    float* w2l  = lds + 33280;

    const int tid = threadIdx.x;
    const int l = tid & 63, w = tid >> 6;           // 8 waves
    const int lg = l >> 4, c16 = l & 15;
    const int mb = blockIdx.x & 3, nb = blockIdx.x >> 2;
    const int m0 = mb * 512, n0 = nb * 4;
    const int mw = w * 64;                          // wave's 64-m base

    // ---- stage A-fragments (Wd) for K=16: entry (mt,kt,l) holds
    //      ch = kt*16 + lg*4 + {0..3} of o = mt*16 + (l&15)   (k = lg*4+b)
    {
        bf16x4* A4 = (bf16x4*)lds;
#pragma unroll
        for (int i = 0; i < 8; ++i) {
            int e = tid + i * 512;                 // 0..4095
            int le = e & 63, kt = (e >> 6) & 7, mt = e >> 9;
            int o = mt * 16 + (le & 15);
            int ch = kt * 16 + (le >> 4) * 4;
            float4 f = *(const float4*)(w1 + o * 384 + 256 + ch);
            union { unsigned d[2]; bf16x4 v; } pk;
            pk.d[0] = (unsigned)f2bf(f.x) | ((unsigned)f2bf(f.y) << 16);
            pk.d[1] = (unsigned)f2bf(f.z) | ((unsigned)f2bf(f.w) << 16);
            A4[e] = pk.v;
        }
    }
    {                                              // qbT[nl][o]
        int o = tid >> 2, nl2 = tid & 3;
        qbT[nl2 * 128 + o] = qb[o * 256 + n0 + nl2];
    }
    if (tid < 128) w2l[tid] = w2[tid];

    // ---- per-lane kh slice -> 64 packed bf16 VGPRs (cold: read only in epi)
    unsigned khp[4][16];
#pragma unroll
    for (int g = 0; g < 4; ++g) {
        const float* kp = kh + (size_t)(m0 + mw + g * 16 + c16);
#pragma unroll
        for (int mt = 0; mt < 8; ++mt) {
            int o = mt * 16 + lg * 4;
            float a0 = kp[(size_t)o * 2048];
            float a1 = kp[(size_t)(o + 1) * 2048];
            float a2 = kp[(size_t)(o + 2) * 2048];
            float a3 = kp[(size_t)(o + 3) * 2048];
            khp[g][mt * 2]     = (unsigned)f2bf(a0) | ((unsigned)f2bf(a1) << 16);
            khp[g][mt * 2 + 1] = (unsigned)f2bf(a2) | ((unsigned)f2bf(a3) << 16);
        }
    }
    __syncthreads();               // A/qbT/w2l staged; ring free
    WAITVM(0);                     // drain khp loads: clean vmcnt baseline
    __builtin_amdgcn_sched_barrier(0);

    f32x4 acc[4][8];
#pragma unroll
    for (int g = 0; g < 4; ++g)
#pragma unroll
        for (int mt = 0; mt < 8; ++mt) acc[g][mt] = (f32x4){0.f, 0.f, 0.f, 0.f};

    const float b2v = b2[0];
    float runmin = 1e30f;

    // slot T = nl*8 + kt: wave w stages rows r = 2w, 2w+1 (ch = kt*16+r),
    // each row = 2KB contiguous global run, stored with 16B-group XOR (r&7)
    // pre-applied to the GLOBAL source (linear LDS dest).
    auto issueS = [&](int T, float* buf) {
        int nl = T >> 3, kt = T & 7;
        const float* basep = dist + (size_t)(n0 + nl) * 2048 + (size_t)m0;
#pragma unroll
        for (int j = 0; j < 2; ++j) {
            int r = w * 2 + j;
            int kr = r & 7;
            const float* g = basep + (size_t)(kt * 16 + r) * (size_t)P_TOT
                                   + (size_t)((l ^ kr) << 2);
            gload16(g, buf + r * 512);
            gload16(g + 256, buf + r * 512 + 256);
        }
    };

    auto epi = [&](int nl) {
        float sps[4];
        const float* qr = qbT + nl * 128;
#pragma unroll
        for (int g = 0; g < 4; ++g) {
            float sp = 0.f;
#pragma unroll
            for (int mt = 0; mt < 8; ++mt) {
                unsigned k01 = khp[g][mt * 2];
                unsigned k23 = khp[g][mt * 2 + 1];
                float kh0 = __uint_as_float(k01 << 16);
                float kh1 = __uint_as_float(k01 & 0xffff0000u);
                float kh2 = __uint_as_float(k23 << 16);
                float kh3 = __uint_as_float(k23 & 0xffff0000u);
                int o = mt * 16 + lg * 4;
                float4 qv = *(const float4*)(qr + o);
                float4 wv = *(const float4*)(w2l + o);
                float t0 = fmaxf(acc[g][mt][0] + qv.x + kh0, 0.f);
                float t1 = fmaxf(acc[g][mt][1] + qv.y + kh1, 0.f);
                float t2 = fmaxf(acc[g][mt][2] + qv.z + kh2, 0.f);
                float t3 = fmaxf(acc[g][mt][3] + qv.w + kh3, 0.f);
                sp = fmaf(wv.x, t0, sp); sp = fmaf(wv.y, t1, sp);
                sp = fmaf(wv.z, t2, sp); sp = fmaf(wv.w, t3, sp);
                acc[g][mt] = (f32x4){0.f, 0.f, 0.f, 0.f};
            }
            sp += __shfl_xor(sp, 16);
            sp += __shfl_xor(sp, 32);
            sps[g] = sp + b2v;
        }
        // lane l writes m = mw + l  (g = lg after the cross-lg reduce)
        float outv = (lg == 0) ? sps[0] : (lg == 1) ? sps[1]
                   : (lg == 2) ? sps[2] : sps[3];
        scores[(size_t)(n0 + nl) * 2048 + (size_t)(m0 + mw) + l] = outv;
        float mn = fminf(fminf(sps[0], sps[1]), fminf(sps[2], sps[3]));
        mn = fminf(mn, __shfl_xor(mn, 1));
        mn = fminf(mn, __shfl_xor(mn, 2));
        mn = fminf(mn, __shfl_xor(mn, 4));
        mn = fminf(mn, __shfl_xor(mn, 8));
        runmin = fminf(runmin, mn);
    };

    float* pF = ring;              // front: holds slot T
    float* pM = ring + 8192;       // T+1
    float* pB = ring + 16384;      // T+2
    issueS(0, pF); issueS(1, pM); issueS(2, pB);

    // STEP T: wait -> barrier -> 32 MFMA (4 col-groups x 8 mt, K=16) on slot T
    //         -> (epi @kt7) -> barrier -> issue T+3 into freed front -> rotate
#define STEP(KT, NL, DO_ISSUE, VM)                                               \
    {                                                                            \
        WAITVM(VM);                                                              \
        __builtin_amdgcn_sched_barrier(0);                                       \
        __builtin_amdgcn_s_barrier();                                            \
        const bf16x4* A4v = (const bf16x4*)lds;                                  \
        bf16x4 af[8];                                                            \
        _Pragma("unroll")                                                        \
        for (int mt = 0; mt < 8; ++mt) af[mt] = A4v[(mt * 8 + (KT)) * 64 + l];   \
        _Pragma("unroll")                                                        \
        for (int g = 0; g < 4; ++g) {                                            \
            float tv[4];                                                         \
            _Pragma("unroll")                                                    \
            for (int b = 0; b < 4; ++b) {                                        \
                int row = lg * 4 + b;                                            \
                int G = (mw + g * 16 + c16) >> 2;                                \
                int idx = row * 512 + ((G ^ (row & 7)) << 2) + (c16 & 3);        \
                tv[b] = pF[idx];                                                 \
            }                                                                    \
            union { unsigned d[2]; bf16x4 v; } bb;                               \
            bb.d[0] = __builtin_amdgcn_perm(__float_as_uint(tv[1]) + 0x8000u,    \
                                            __float_as_uint(tv[0]) + 0x8000u,    \
                                            0x07060302u);                        \
            bb.d[1] = __builtin_amdgcn_perm(__float_as_uint(tv[3]) + 0x8000u,    \
                                            __float_as_uint(tv[2]) + 0x8000u,    \
                                            0x07060302u);                        \
            _Pragma("unroll")                                                    \
            for (int mt = 0; mt < 8; ++mt)                                       \
                acc[g][mt] = MFMA16(af[mt], bb.v, acc[g][mt]);                   \
        }                                                                        \
        if ((KT) == 7) epi(NL);                                                  \
        __builtin_amdgcn_s_barrier();                                            \
        if (DO_ISSUE) issueS((NL) * 8 + (KT) + 3, pF);                           \
        { float* t_ = pF; pF = pM; pM = pB; pB = t_; }                           \
    }

    STEP(0, 0, 1, 8) STEP(1, 0, 1, 8) STEP(2, 0, 1, 8) STEP(3, 0, 1, 8)
    STEP(4, 0, 1, 8) STEP(5, 0, 1, 8) STEP(6, 0, 1, 8) STEP(7, 0, 1, 8)
    STEP(0, 1, 1, 8) STEP(1, 1, 1, 8) STEP(2, 1, 1, 8) STEP(3, 1, 1, 8)
    STEP(4, 1, 1, 8) STEP(5, 1, 1, 8) STEP(6, 1, 1, 8) STEP(7, 1, 1, 8)
    STEP(0, 2, 1, 8) STEP(1, 2, 1, 8) STEP(2, 2, 1, 8) STEP(3, 2, 1, 8)
    STEP(4, 2, 1, 8) STEP(5, 2, 1, 8) STEP(6, 2, 1, 8) STEP(7, 2, 1, 8)
    STEP(0, 3, 1, 8) STEP(1, 3, 1, 8) STEP(2, 3, 1, 8) STEP(3, 3, 1, 8)
    STEP(4, 3, 1, 8)                  // T=28, issues T=31
    STEP(5, 3, 0, 8)                  // T=29
    STEP(6, 3, 0, 4)                  // T=30
    STEP(7, 3, 0, 0)                  // T=31
#undef STEP

    union { float f; unsigned u; } e; e.f = runmin;
    unsigned key = (e.u & 0x80000000u) ? ~e.u : (e.u | 0x80000000u);
    if (l == 0) atomicMin(minw, key);
}

// ---------------- tail: mask + softmax + message + mlp1 + mlp2 ----------------
__global__ __launch_bounds__(256) void k_tail(
    float* __restrict__ scores, const int* __restrict__ mask,
    const float* __restrict__ src, const unsigned* __restrict__ minw,
    const float* __restrict__ w3, const float* __restrict__ w4,
    const float* __restrict__ b4, const float* __restrict__ p1,
    float* __restrict__ out) {
    __shared__ float sc[2][2048];
    __shared__ float red[2][8];
    __shared__ float msgl[2][128];
    __shared__ float hidl[2][256];
    const int t = threadIdx.x, l = t & 63, wv = t >> 6;
    const int n0 = blockIdx.x * 2;

    unsigned key = *minw;
    union { float f; unsigned u; } d;
    d.u = (key & 0x80000000u) ? (key ^ 0x80000000u) : ~key;
    const float neg = d.f - 20.f;

#pragma unroll
    for (int nn = 0; nn < 2; ++nn) {
        int n = n0 + nn;
        float lmax = -1e30f;
#pragma unroll
        for (int i = 0; i < 8; ++i) {
            int m = t + i * 256;
            float v = scores[n * 2048 + m];
            if (!mask[n * 2048 + m]) v += neg;
            scores[n * 2048 + m] = v;      // final (masked) scores out
            sc[nn][m] = v;
            lmax = fmaxf(lmax, v);
        }
#pragma unroll
        for (int off = 1; off < 64; off <<= 1) lmax = fmaxf(lmax, __shfl_xor(lmax, off));
        if (l == 0) red[nn][wv] = lmax;
    }
    __syncthreads();
    float smax[2], lsum[2] = {0.f, 0.f};
#pragma unroll
    for (int nn = 0; nn < 2; ++nn)
        smax[nn] = fmaxf(fmaxf(red[nn][0], red[nn][1]), fmaxf(red[nn][2], red[nn][3]));
#pragma unroll
    for (int nn = 0; nn < 2; ++nn) {
#pragma unroll
        for (int i = 0; i < 8; ++i) {
            int m = t + i * 256;
            float e = __expf(sc[nn][m] - smax[nn]);
            sc[nn][m] = e;
            lsum[nn] += e;
        }
#pragma unroll
        for (int off = 1; off < 64; off <<= 1) lsum[nn] += __shfl_xor(lsum[nn], off);
        if (l == 0) red[nn][4 + wv] = lsum[nn];
    }
    __syncthreads();
    const float rinv0 = 1.f / (red[0][4] + red[0][5] + red[0][6] + red[0][7]);
    const float rinv1 = 1.f / (red[1][4] + red[1][5] + red[1][6] + red[1][7]);

    for (int dd = 0; dd < 32; ++dd) {
        int dch = wv * 32 + dd;
        const float* sr = src + dch * 2048;
        float pa = 0.f, pb = 0.f;
#pragma unroll
        for (int j = 0; j < 32; ++j) {
            int mm = l + j * 64;
            float s = sr[mm];
            pa = fmaf(sc[0][mm], s, pa);
            pb = fmaf(sc[1][mm], s, pb);
        }
#pragma unroll
        for (int off = 1; off < 64; off <<= 1) {
            pa += __shfl_xor(pa, off);
            pb += __shfl_xor(pb, off);
        }
        if (l == 0) { msgl[0][dch] = pa * rinv0; msgl[1][dch] = pb * rinv1; }
    }
    __syncthreads();

    {
        int o = t;
        const float* wr = w3 + o * 256 + 128;
        float a0 = p1[o * 256 + n0];
        float a1 = p1[o * 256 + n0 + 1];
#pragma unroll
        for (int c = 0; c < 128; c += 4) {
            float4 w4v = *(const float4*)(wr + c);
            a0 = fmaf(w4v.x, msgl[0][c], a0);     a1 = fmaf(w4v.x, msgl[1][c], a1);
            a0 = fmaf(w4v.y, msgl[0][c + 1], a0); a1 = fmaf(w4v.y, msgl[1][c + 1], a1);
            a0 = fmaf(w4v.z, msgl[0][c + 2], a0); a1 = fmaf(w4v.z, msgl[1][c + 2], a1);
            a0 = fmaf(w4v.w, msgl[0][c + 3], a0); a1 = fmaf(w4v.w, msgl[1][c + 3], a1);
        }
        hidl[0][o] = fmaxf(a0, 0.f);
        hidl[1][o] = fmaxf(a1, 0.f);
    }
    __syncthreads();

    {
        int o = t & 127, nn = t >> 7;
        const float* wr = w4 + o * 256;
        const float* hr = hidl[nn];
        float acc = b4[o];
#pragma unroll
        for (int c = 0; c < 256; c += 4) {
            float4 w4v = *(const float4*)(wr + c);
            acc = fmaf(w4v.x, hr[c], acc);
            acc = fmaf(w4v.y, hr[c + 1], acc);
            acc = fmaf(w4v.z, hr[c + 2], acc);
            acc = fmaf(w4v.w, hr[c + 3], acc);
        }
        out[o * 256 + n0 + nn] = acc;
    }
}

extern "C" void kernel_launch(void* const* d_in, const int* in_sizes, int n_in,
                              void* d_out, int out_size, void* d_ws, size_t ws_size,
                              hipStream_t stream) {
    const float* x      = (const float*)d_in[0];
    const float* source = (const float*)d_in[1];
    const float* dist   = (const float*)d_in[2];
    const int*   mask   = (const int*)d_in[3];
    const float* w1     = (const float*)d_in[4];
    const float* b1     = (const float*)d_in[5];
    const float* w2     = (const float*)d_in[6];
    const float* b2     = (const float*)d_in[7];
    const float* w3     = (const float*)d_in[8];
    const float* b3     = (const float*)d_in[9];
    const float* w4     = (const float*)d_in[10];
    const float* b4     = (const float*)d_in[11];

    float* outp    = (float*)d_out;          // 128*256
    float* scoresp = outp + 32768;           // 256*2048 (raw, then masked in-place)

    float* ws   = (float*)d_ws;
    float* qb   = ws;                 // 32768
    float* kh   = ws + 32768;         // 262144
    float* p1   = ws + 294912;        // 65536
    unsigned* minw = (unsigned*)(ws + 360448);

    k_prep<<<1408, 256, 0, stream>>>(w1, x, b1, source, w3, b3, qb, kh, p1, minw);
    k_scores<<<256, 512, 0, stream>>>(dist, w1, qb, kh, w2, b2, scoresp, minw);
    k_tail<<<128, 256, 0, stream>>>(scoresp, mask, source, minw, w3, w4, b4, p1, outp);
}

// Round 17
// 119.528 us; speedup vs baseline: 2.6519x; 2.6519x over previous
//
#include <hip/hip_runtime.h>
#include <hip/hip_bf16.h>

#define D_ 128
#define NQ_ 256
#define NK_ 2048
#define P_TOT (NQ_ * NK_)   // 524288

typedef float f32x4 __attribute__((ext_vector_type(4)));
typedef short bf16x8 __attribute__((ext_vector_type(8)));

__device__ __forceinline__ unsigned short f2bf(float x) {
    union { float f; unsigned u; } v; v.f = x;
    unsigned r = v.u + 0x7FFFu + ((v.u >> 16) & 1u);   // RNE
    return (unsigned short)(r >> 16);
}

// async global->LDS, 16B per lane (wave-uniform LDS base, per-lane global addr)
__device__ __forceinline__ void gload16(const float* g, float* l) {
    __builtin_amdgcn_global_load_lds((const __attribute__((address_space(1))) void*)g,
                                     (__attribute__((address_space(3))) void*)l, 16, 0, 0);
}

#define WAITVM_(n) asm volatile("s_waitcnt vmcnt(" #n ")" ::: "memory")
#define WAITVM(n) WAITVM_(n)

// ---------------- prep: minw init + qb + kh + p1 ----------------
__global__ __launch_bounds__(256) void k_prep(
    const float* __restrict__ w1, const float* __restrict__ x,
    const float* __restrict__ b1, const float* __restrict__ src,
    const float* __restrict__ w3, const float* __restrict__ b3,
    float* __restrict__ qb, float* __restrict__ kh, float* __restrict__ p1,
    unsigned* __restrict__ minw) {
    int b = blockIdx.x, t = threadIdx.x;
    if (b == 0 && t == 0) *minw = 0xFFFFFFFFu;
    if (b < 128) {
        int o = b, n = t;
        const float* wr = w1 + o * 384;
        float acc = b1[o];
#pragma unroll 4
        for (int c = 0; c < 128; ++c) acc = fmaf(wr[c], x[c * 256 + n], acc);
        qb[o * 256 + n] = acc;
    } else if (b < 1152) {
        int idx = (b - 128) * 256 + t;
        int o = idx >> 11, m = idx & 2047;
        const float* wr = w1 + o * 384 + 128;
        float acc = 0.f;
#pragma unroll 4
        for (int c = 0; c < 128; ++c) acc = fmaf(wr[c], src[c * 2048 + m], acc);
        kh[o * 2048 + m] = acc;
    } else {
        int o = b - 1152, n = t;
        const float* wr = w3 + o * 256;
        float acc = b3[o];
#pragma unroll 4
        for (int c = 0; c < 128; ++c) acc = fmaf(wr[c], x[c * 256 + n], acc);
        p1[o * 256 + n] = acc;
    }
}

// ---------------- scores (raw) + global min ----------------
// FINAL (R9 configuration, best measured: 119.8 us total).
// Per block: 256-m x 8-n window. Tile = one (n, 32ch) slab [32][256] f32,
// staged as full 1KB rows via global_load_lds. 3-deep LDS ring, prefetch
// distance 3, counted vmcnt(8). A-fragments live in a PERSISTENT LDS region
// and are ds_read per step (NOT in VGPRs) -- kills scratch spills (R8).
// Measured-null alternatives: deeper ring (R10), 2 blocks/CU (R11),
// reg-staging (R13); 2KB-run probes (R12/R14/R16) void on allocator clamps.
// ~3 TB/s counted is the practical ceiling of this staged strided pattern.
__global__ __launch_bounds__(512, 2) void k_scores(
    const float* __restrict__ dist, const float* __restrict__ w1,
    const float* __restrict__ qb, const float* __restrict__ kh,
    const float* __restrict__ w2, const float* __restrict__ b2,
    float* __restrict__ scores, unsigned* __restrict__ minw) {
    __shared__ __align__(16) float lds[33920];   // 135680 B
    // [0..8191]      : A-fragments (bf16x8[2048]), persistent
    // [8192..32767]  : 3 x [32][256] f32 tile ring
    // [32768..33791] : qbT [8][128]
    // [33792..33919] : w2l [128]
    float* bufs = lds + 8192;
    float* qbT  = lds + 32768;
    float* w2l  = lds + 33792;

    const int tid = threadIdx.x;
    const int l = tid & 63, wid = tid >> 6;
    const int lg = l >> 4, c16 = l & 15;
    const int mb = blockIdx.x & 7, nb = blockIdx.x >> 3;
    const int m0 = mb * 256, n0 = nb * 8;

    // ---- cooperative staging: A-fragments (Wd, persistent), qbT, w2 ----
    {
        bf16x8* ldsA = (bf16x8*)lds;
#pragma unroll
        for (int i = 0; i < 4; ++i) {
            int s = tid + i * 512;
            int o = s >> 4, oct = s & 15;
            const float* gp = w1 + o * 384 + 256 + oct * 8;
            float4 f0 = *(const float4*)gp;
            float4 f1 = *(const float4*)(gp + 4);
            union { bf16x8 v; unsigned short u[8]; } pk;
            pk.u[0] = f2bf(f0.x); pk.u[1] = f2bf(f0.y); pk.u[2] = f2bf(f0.z); pk.u[3] = f2bf(f0.w);
            pk.u[4] = f2bf(f1.x); pk.u[5] = f2bf(f1.y); pk.u[6] = f2bf(f1.z); pk.u[7] = f2bf(f1.w);
            int mt = o >> 4, kt = oct >> 2;
            int lane2 = ((oct & 3) << 4) | (o & 15);   // k(lg,b) = lg*8 + b
            ldsA[(mt * 4 + kt) * 64 + lane2] = pk.v;
        }
    }
#pragma unroll
    for (int jj = 0; jj < 2; ++jj) {
        int e = tid + jj * 512;
        int o = e >> 3, nl2 = e & 7;
        qbT[nl2 * 128 + o] = qb[o * 256 + n0 + nl2];
    }
    if (tid < 128) w2l[tid] = w2[tid];

    // ---- per-lane kh slice -> 32 packed bf16 VGPRs ----
    unsigned khp[2][16];
#pragma unroll
    for (int s = 0; s < 2; ++s) {
        const float* kp = kh + (size_t)(m0 + wid * 32 + s * 16 + c16);
#pragma unroll
        for (int mt = 0; mt < 8; ++mt) {
            float a0 = kp[(size_t)(mt * 16 + lg * 4) * 2048];
            float a1 = kp[(size_t)(mt * 16 + lg * 4 + 1) * 2048];
            float a2 = kp[(size_t)(mt * 16 + lg * 4 + 2) * 2048];
            float a3 = kp[(size_t)(mt * 16 + lg * 4 + 3) * 2048];
            khp[s][mt * 2]     = (unsigned)f2bf(a0) | ((unsigned)f2bf(a1) << 16);
            khp[s][mt * 2 + 1] = (unsigned)f2bf(a2) | ((unsigned)f2bf(a3) << 16);
        }
    }
    __syncthreads();               // A/qbT/w2l staged; ring buffers free
    WAITVM(0);                     // clean vmcnt baseline before tile issue
    __builtin_amdgcn_sched_barrier(0);

    f32x4 acc[2][8];
#pragma unroll
    for (int s = 0; s < 2; ++s)
#pragma unroll
        for (int mt = 0; mt < 8; ++mt) acc[s][mt] = (f32x4){0.f, 0.f, 0.f, 0.f};

    const float b2v = b2[0];
    float runmin = 1e30f;

    // tile t: n_l = t>>2, cq = t&3
    auto issueT = [&](int t, float* buf) {
        int n_l = t >> 2;
        int cq = t & 3;
        const float* basep = dist + (size_t)(n0 + n_l) * 2048 + (size_t)m0;
#pragma unroll
        for (int j = 0; j < 4; ++j) {
            int row = wid * 4 + j;
            int x = ((row >> 3) & 1) << 2;
            gload16(basep + (size_t)(cq * 32 + row) * (size_t)P_TOT + ((l ^ x) << 2),
                    buf + row * 256);
        }
    };

    auto epi = [&](int nl) {
        const float* qr = qbT + nl * 128;
        float sc2[2];
#pragma unroll
        for (int s = 0; s < 2; ++s) {
            float sp = 0.f;
#pragma unroll
            for (int mt = 0; mt < 8; ++mt) {
                unsigned k01 = khp[s][mt * 2];
                unsigned k23 = khp[s][mt * 2 + 1];
                float kh0 = __uint_as_float(k01 << 16);
                float kh1 = __uint_as_float(k01 & 0xffff0000u);
                float kh2 = __uint_as_float(k23 << 16);
                float kh3 = __uint_as_float(k23 & 0xffff0000u);
                int o = mt * 16 + lg * 4;
                float4 qv = *(const float4*)(qr + o);
                float4 wv = *(const float4*)(w2l + o);
                float t0 = fmaxf(acc[s][mt][0] + qv.x + kh0, 0.f);
                float t1 = fmaxf(acc[s][mt][1] + qv.y + kh1, 0.f);
                float t2 = fmaxf(acc[s][mt][2] + qv.z + kh2, 0.f);
                float t3 = fmaxf(acc[s][mt][3] + qv.w + kh3, 0.f);
                sp = fmaf(wv.x, t0, sp); sp = fmaf(wv.y, t1, sp);
                sp = fmaf(wv.z, t2, sp); sp = fmaf(wv.w, t3, sp);
                acc[s][mt] = (f32x4){0.f, 0.f, 0.f, 0.f};
            }
            sp += __shfl_xor(sp, 16);
            sp += __shfl_xor(sp, 32);
            sc2[s] = sp + b2v;
        }
        float wv = (l < 16) ? sc2[0] : sc2[1];
        if (l < 32) scores[(size_t)(n0 + nl) * 2048 + (size_t)(m0 + wid * 32) + l] = wv;
        float mn = fminf(sc2[0], sc2[1]);
        mn = fminf(mn, __shfl_xor(mn, 1));
        mn = fminf(mn, __shfl_xor(mn, 2));
        mn = fminf(mn, __shfl_xor(mn, 4));
        mn = fminf(mn, __shfl_xor(mn, 8));
        runmin = fminf(runmin, mn);
    };

    float* pF = bufs;              // front: holds tile t
    float* pM = bufs + 8192;       // t+1
    float* pB = bufs + 16384;      // t+2
    issueT(0, pF); issueT(1, pM); issueT(2, pB);

    // STEP: wait tile t -> barrier -> compute (A from LDS) -> (epi) -> barrier
    //       -> issue t+3 into freed front -> rotate ring
#define STEP(CQ, NL, DO_ISSUE, VM)                                               \
    {                                                                            \
        WAITVM(VM);                                                              \
        __builtin_amdgcn_sched_barrier(0);                                       \
        __builtin_amdgcn_s_barrier();                                            \
        const bf16x8* ldsAv = (const bf16x8*)lds;                                \
        bf16x8 af[8];                                                            \
        _Pragma("unroll")                                                        \
        for (int mt = 0; mt < 8; ++mt) af[mt] = ldsAv[(mt * 4 + (CQ)) * 64 + l]; \
        _Pragma("unroll")                                                        \
        for (int s = 0; s < 2; ++s) {                                            \
            const int grpx = (wid * 8 + s * 4 + (c16 >> 2)) ^ ((lg & 1) << 2);   \
            const float* rp = pF + lg * 2048 + grpx * 4 + (c16 & 3);             \
            float tv[8];                                                         \
            _Pragma("unroll")                                                    \
            for (int b = 0; b < 8; ++b) tv[b] = rp[b * 256];                     \
            union { unsigned d[4]; bf16x8 v; } bb;                               \
            _Pragma("unroll")                                                    \
            for (int i = 0; i < 4; ++i) {                                        \
                unsigned r0 = __float_as_uint(tv[2 * i])     + 0x8000u;          \
                unsigned r1 = __float_as_uint(tv[2 * i + 1]) + 0x8000u;          \
                bb.d[i] = __builtin_amdgcn_perm(r1, r0, 0x07060302u);            \
            }                                                                    \
            _Pragma("unroll")                                                    \
            for (int mt = 0; mt < 8; ++mt)                                       \
                acc[s][mt] = __builtin_amdgcn_mfma_f32_16x16x32_bf16(            \
                    af[mt], bb.v, acc[s][mt], 0, 0, 0);                          \
        }                                                                        \
        if ((CQ) == 3) epi(NL);                                                  \
        __builtin_amdgcn_s_barrier();                                            \
        if (DO_ISSUE) issueT((NL) * 4 + (CQ) + 3, pF);                           \
        float* t_ = pF; pF = pM; pM = pB; pB = t_;                               \
    }

    for (int nl = 0; nl < 7; ++nl) {    // t = 0..27, all issue t+3, vm 8
        STEP(0, nl, true, 8)
        STEP(1, nl, true, 8)
        STEP(2, nl, true, 8)
        STEP(3, nl, true, 8)
    }
    STEP(0, 7, true,  8)   // t=28, issues t=31
    STEP(1, 7, false, 8)   // t=29
    STEP(2, 7, false, 4)   // t=30
    STEP(3, 7, false, 0)   // t=31
#undef STEP

    union { float f; unsigned u; } e; e.f = runmin;
    unsigned key = (e.u & 0x80000000u) ? ~e.u : (e.u | 0x80000000u);
    if (l == 0) atomicMin(minw, key);
}

// ---------------- tail: mask + softmax + message + mlp1 + mlp2 ----------------
__global__ __launch_bounds__(256) void k_tail(
    float* __restrict__ scores, const int* __restrict__ mask,
    const float* __restrict__ src, const unsigned* __restrict__ minw,
    const float* __restrict__ w3, const float* __restrict__ w4,
    const float* __restrict__ b4, const float* __restrict__ p1,
    float* __restrict__ out) {
    __shared__ float sc[2][2048];
    __shared__ float red[2][8];
    __shared__ float msgl[2][128];
    __shared__ float hidl[2][256];
    const int t = threadIdx.x, l = t & 63, wv = t >> 6;
    const int n0 = blockIdx.x * 2;

    unsigned key = *minw;
    union { float f; unsigned u; } d;
    d.u = (key & 0x80000000u) ? (key ^ 0x80000000u) : ~key;
    const float neg = d.f - 20.f;

#pragma unroll
    for (int nn = 0; nn < 2; ++nn) {
        int n = n0 + nn;
        float lmax = -1e30f;
#pragma unroll
        for (int i = 0; i < 8; ++i) {
            int m = t + i * 256;
            float v = scores[n * 2048 + m];
            if (!mask[n * 2048 + m]) v += neg;
            scores[n * 2048 + m] = v;      // final (masked) scores out
            sc[nn][m] = v;
            lmax = fmaxf(lmax, v);
        }
#pragma unroll
        for (int off = 1; off < 64; off <<= 1) lmax = fmaxf(lmax, __shfl_xor(lmax, off));
        if (l == 0) red[nn][wv] = lmax;
    }
    __syncthreads();
    float smax[2], lsum[2] = {0.f, 0.f};
#pragma unroll
    for (int nn = 0; nn < 2; ++nn)
        smax[nn] = fmaxf(fmaxf(red[nn][0], red[nn][1]), fmaxf(red[nn][2], red[nn][3]));
#pragma unroll
    for (int nn = 0; nn < 2; ++nn) {
#pragma unroll
        for (int i = 0; i < 8; ++i) {
            int m = t + i * 256;
            float e = __expf(sc[nn][m] - smax[nn]);
            sc[nn][m] = e;
            lsum[nn] += e;
        }
#pragma unroll
        for (int off = 1; off < 64; off <<= 1) lsum[nn] += __shfl_xor(lsum[nn], off);
        if (l == 0) red[nn][4 + wv] = lsum[nn];
    }
    __syncthreads();
    const float rinv0 = 1.f / (red[0][4] + red[0][5] + red[0][6] + red[0][7]);
    const float rinv1 = 1.f / (red[1][4] + red[1][5] + red[1][6] + red[1][7]);

    for (int dd = 0; dd < 32; ++dd) {
        int dch = wv * 32 + dd;
        const float* sr = src + dch * 2048;
        float pa = 0.f, pb = 0.f;
#pragma unroll
        for (int j = 0; j < 32; ++j) {
            int mm = l + j * 64;
            float s = sr[mm];
            pa = fmaf(sc[0][mm], s, pa);
            pb = fmaf(sc[1][mm], s, pb);
        }
#pragma unroll
        for (int off = 1; off < 64; off <<= 1) {
            pa += __shfl_xor(pa, off);
            pb += __shfl_xor(pb, off);
        }
        if (l == 0) { msgl[0][dch] = pa * rinv0; msgl[1][dch] = pb * rinv1; }
    }
    __syncthreads();

    {
        int o = t;
        const float* wr = w3 + o * 256 + 128;
        float a0 = p1[o * 256 + n0];
        float a1 = p1[o * 256 + n0 + 1];
#pragma unroll
        for (int c = 0; c < 128; c += 4) {
            float4 w4v = *(const float4*)(wr + c);
            a0 = fmaf(w4v.x, msgl[0][c], a0);     a1 = fmaf(w4v.x, msgl[1][c], a1);
            a0 = fmaf(w4v.y, msgl[0][c + 1], a0); a1 = fmaf(w4v.y, msgl[1][c + 1], a1);
            a0 = fmaf(w4v.z, msgl[0][c + 2], a0); a1 = fmaf(w4v.z, msgl[1][c + 2], a1);
            a0 = fmaf(w4v.w, msgl[0][c + 3], a0); a1 = fmaf(w4v.w, msgl[1][c + 3], a1);
        }
        hidl[0][o] = fmaxf(a0, 0.f);
        hidl[1][o] = fmaxf(a1, 0.f);
    }
    __syncthreads();

    {
        int o = t & 127, nn = t >> 7;
        const float* wr = w4 + o * 256;
        const float* hr = hidl[nn];
        float acc = b4[o];
#pragma unroll
        for (int c = 0; c < 256; c += 4) {
            float4 w4v = *(const float4*)(wr + c);
            acc = fmaf(w4v.x, hr[c], acc);
            acc = fmaf(w4v.y, hr[c + 1], acc);
            acc = fmaf(w4v.z, hr[c + 2], acc);
            acc = fmaf(w4v.w, hr[c + 3], acc);
        }
        out[o * 256 + n0 + nn] = acc;
    }
}

extern "C" void kernel_launch(void* const* d_in, const int* in_sizes, int n_in,
                              void* d_out, int out_size, void* d_ws, size_t ws_size,
                              hipStream_t stream) {
    const float* x      = (const float*)d_in[0];
    const float* source = (const float*)d_in[1];
    const float* dist   = (const float*)d_in[2];
    const int*   mask   = (const int*)d_in[3];
    const float* w1     = (const float*)d_in[4];
    const float* b1     = (const float*)d_in[5];
    const float* w2     = (const float*)d_in[6];
    const float* b2     = (const float*)d_in[7];
    const float* w3     = (const float*)d_in[8];
    const float* b3     = (const float*)d_in[9];
    const float* w4     = (const float*)d_in[10];
    const float* b4     = (const float*)d_in[11];

    float* outp    = (float*)d_out;          // 128*256
    float* scoresp = outp + 32768;           // 256*2048 (raw, then masked in-place)

    float* ws   = (float*)d_ws;
    float* qb   = ws;                 // 32768
    float* kh   = ws + 32768;         // 262144
    float* p1   = ws + 294912;        // 65536
    unsigned* minw = (unsigned*)(ws + 360448);

    k_prep<<<1408, 256, 0, stream>>>(w1, x, b1, source, w3, b3, qb, kh, p1, minw);
    k_scores<<<256, 512, 0, stream>>>(dist, w1, qb, kh, w2, b2, scoresp, minw);
    k_tail<<<128, 256, 0, stream>>>(scoresp, mask, source, minw, w3, w4, b4, p1, outp);
}